// Round 6
// baseline (287.755 us; speedup 1.0000x reference)
//
#include <hip/hip_runtime.h>
#include <math.h>

#define BB 16
#define MM 2048
#define SS 6
#define EE 128
#define LCC 512
#define VV 32000
#define NTB 256        // tail grid: 16 b x 16 segments, must all be co-resident

typedef __attribute__((ext_vector_type(8))) __bf16 bf16x8;
typedef __attribute__((ext_vector_type(4))) float f32x4;

#define XS_STRIDE 264   // 256+8 bf16 pad
#define HS_STRIDE 136   // 128+8 bf16 pad
#define MS_STRIDE 136   // tail LDS row stride (odd*8 -> rows offset 4 banks)

// ---------------------------------------------------------------------------
// megaprep: fp32->bf16 of C[0..3), dh, tf; weight transpose; uqA=query, uqB=0;
// zero the grid-barrier counters (ws is re-poisoned 0xAA before every launch).
// ---------------------------------------------------------------------------
static __device__ inline void cvt8(const float* __restrict__ src, __bf16* __restrict__ dst) {
    const float4 a = *(const float4*)src;
    const float4 b = *(const float4*)(src + 4);
    bf16x8 o;
    o[0] = (__bf16)a.x; o[1] = (__bf16)a.y; o[2] = (__bf16)a.z; o[3] = (__bf16)a.w;
    o[4] = (__bf16)b.x; o[5] = (__bf16)b.y; o[6] = (__bf16)b.z; o[7] = (__bf16)b.w;
    *(bf16x8*)dst = o;
}

#define N_C8  (3 * VV * EE / 8)        // 1,536,000
#define N_D8  (BB * LCC * EE / 8)      // 131,072
#define N_T8  (BB * EE / 8)            // 256
#define N_W1  (256 * 128)              // 32,768
#define N_W2  (128 * 128)              // 16,384
#define N_UQ  (BB * EE)                // 2,048
#define N_PREP (N_C8 + N_D8 + N_T8 + N_W1 + N_W2 + N_UQ + 256)

__global__ __launch_bounds__(256)
void megaprep(const float* __restrict__ C, const float* __restrict__ dh,
              const float* __restrict__ tf, const float* __restrict__ W1,
              const float* __restrict__ W2, const float* __restrict__ query,
              __bf16* __restrict__ Cb, __bf16* __restrict__ dhb,
              __bf16* __restrict__ tfb, __bf16* __restrict__ w1t,
              __bf16* __restrict__ w2t, float* __restrict__ uqA,
              float* __restrict__ uqB, unsigned* __restrict__ syncv)
{
    int i = blockIdx.x * 256 + threadIdx.x;
    if (i < N_C8) { cvt8(C + (size_t)i * 8, Cb + (size_t)i * 8); return; }
    i -= N_C8;
    if (i < N_D8) { cvt8(dh + (size_t)i * 8, dhb + (size_t)i * 8); return; }
    i -= N_D8;
    if (i < N_T8) { cvt8(tf + i * 8, tfb + i * 8); return; }
    i -= N_T8;
    if (i < N_W1) { const int n = i >> 8, k = i & 255; w1t[i] = (__bf16)W1[k * EE + n]; return; }
    i -= N_W1;
    if (i < N_W2) { const int n = i >> 7, k = i & 127; w2t[i] = (__bf16)W2[k * EE + n]; return; }
    i -= N_W2;
    if (i < N_UQ) { uqA[i] = query[i]; uqB[i] = 0.f; return; }
    i -= N_UQ;
    if (i < 2) syncv[i] = 0u;
}

// ---------------------------------------------------------------------------
// Fused embed gather-sum + add_lm + MFMA MLP (R4-exact, 48.8 us known-good).
// hop 0: logits0 in-register, m0 never stored. hops 1,2: Y -> mout bf16.
// ---------------------------------------------------------------------------
__global__ __launch_bounds__(256)
void embed_mlp_mfma(const int* __restrict__ story,
                    const int* __restrict__ kb_len,
                    const int* __restrict__ conv_len,
                    const __bf16* __restrict__ Cb,
                    const __bf16* __restrict__ dhb,
                    const __bf16* __restrict__ tfb,
                    const __bf16* __restrict__ w1t, const float* __restrict__ b1,
                    const __bf16* __restrict__ w2t, const float* __restrict__ b2,
                    const float* __restrict__ gp, const float* __restrict__ query,
                    __bf16* __restrict__ mout, float* __restrict__ lbuf0)
{
    __shared__ __bf16 Xs[32 * XS_STRIDE];   // 16,896 B
    __shared__ __bf16 Hs[32 * HS_STRIDE];   //  8,704 B
    __shared__ int    sidx[32 * SS];
    float* plog = (float*)Hs;               // aliases Hs after GEMM2 reads

    const int bid  = blockIdx.x;
    const int hop  = bid >> 10;
    const int row0 = (bid & 1023) * 32;
    const int b    = row0 >> 11;
    const int tid  = threadIdx.x;

    const __bf16* Ck = Cb + (size_t)hop * VV * EE;

    for (int i = tid; i < 32 * SS; i += 256) sidx[i] = story[(size_t)row0 * SS + i];

    const int kb   = kb_len[b];
    const int cl   = conv_len[b];
    const int rgrp = tid >> 4;
    const int e8   = (tid & 15) * 8;
    const bf16x8 tf8 = *(const bf16x8*)&tfb[b * EE + e8];
    __syncthreads();

    bf16x8 g[2][SS], dv[2];
    #pragma unroll
    for (int p = 0; p < 2; ++p) {
        const int r = p * 16 + rgrp;
        const int* si = &sidx[r * SS];
        #pragma unroll
        for (int s = 0; s < SS; ++s)
            g[p][s] = *(const bf16x8*)&Ck[(size_t)si[s] * EE + e8];
        const int j = ((row0 + r) & (MM - 1)) - kb;
        if (j >= 0 && j < cl) {
            dv[p] = *(const bf16x8*)&dhb[((size_t)b * LCC + j) * EE + e8];
        } else {
            bf16x8 z;
            #pragma unroll
            for (int q = 0; q < 8; ++q) z[q] = (__bf16)0.f;
            dv[p] = z;
        }
    }
    #pragma unroll
    for (int p = 0; p < 2; ++p) {
        const int r = p * 16 + rgrp;
        bf16x8 pk;
        #pragma unroll
        for (int q = 0; q < 8; ++q) {
            float s = (float)dv[p][q];
            #pragma unroll
            for (int s6 = 0; s6 < SS; ++s6) s += (float)g[p][s6][q];
            pk[q] = (__bf16)s;
        }
        *(bf16x8*)&Xs[r * XS_STRIDE + e8]      = pk;
        *(bf16x8*)&Xs[r * XS_STRIDE + EE + e8] = tf8;
    }
    __syncthreads();

    const int w       = tid >> 6;
    const int lane    = tid & 63;
    const int lr      = lane & 15;
    const int lk      = lane >> 4;
    const int colbase = w * 32;

    f32x4 acc1[2][2];
    #pragma unroll
    for (int i = 0; i < 2; ++i)
        #pragma unroll
        for (int j = 0; j < 2; ++j) acc1[i][j] = (f32x4){0.f, 0.f, 0.f, 0.f};

    for (int ks = 0; ks < 8; ++ks) {
        bf16x8 a[2], bw[2];
        #pragma unroll
        for (int mt = 0; mt < 2; ++mt)
            a[mt] = *(const bf16x8*)&Xs[(mt * 16 + lr) * XS_STRIDE + ks * 32 + lk * 8];
        #pragma unroll
        for (int nt = 0; nt < 2; ++nt)
            bw[nt] = *(const bf16x8*)&w1t[(size_t)(colbase + nt * 16 + lr) * 256 + ks * 32 + lk * 8];
        #pragma unroll
        for (int mt = 0; mt < 2; ++mt)
            #pragma unroll
            for (int nt = 0; nt < 2; ++nt)
                acc1[mt][nt] = __builtin_amdgcn_mfma_f32_16x16x32_bf16(a[mt], bw[nt], acc1[mt][nt], 0, 0, 0);
    }
    {
        const float b1v[2] = { b1[colbase + lr], b1[colbase + 16 + lr] };
        #pragma unroll
        for (int mt = 0; mt < 2; ++mt)
            #pragma unroll
            for (int nt = 0; nt < 2; ++nt)
                #pragma unroll
                for (int reg = 0; reg < 4; ++reg) {
                    float h = acc1[mt][nt][reg] + b1v[nt];
                    h = (h > 0.f) ? h : 0.1f * h;
                    Hs[(mt * 16 + lk * 4 + reg) * HS_STRIDE + colbase + nt * 16 + lr] = (__bf16)h;
                }
    }
    __syncthreads();

    f32x4 acc2[2][2];
    #pragma unroll
    for (int i = 0; i < 2; ++i)
        #pragma unroll
        for (int j = 0; j < 2; ++j) acc2[i][j] = (f32x4){0.f, 0.f, 0.f, 0.f};

    for (int ks = 0; ks < 4; ++ks) {
        bf16x8 a[2], bw[2];
        #pragma unroll
        for (int mt = 0; mt < 2; ++mt)
            a[mt] = *(const bf16x8*)&Hs[(mt * 16 + lr) * HS_STRIDE + ks * 32 + lk * 8];
        #pragma unroll
        for (int nt = 0; nt < 2; ++nt)
            bw[nt] = *(const bf16x8*)&w2t[(size_t)(colbase + nt * 16 + lr) * 128 + ks * 32 + lk * 8];
        #pragma unroll
        for (int mt = 0; mt < 2; ++mt)
            #pragma unroll
            for (int nt = 0; nt < 2; ++nt)
                acc2[mt][nt] = __builtin_amdgcn_mfma_f32_16x16x32_bf16(a[mt], bw[nt], acc2[mt][nt], 0, 0, 0);
    }

    const float b2v[2] = { b2[colbase + lr], b2[colbase + 16 + lr] };

    if (hop == 0) {
        const float qv0 = query[b * EE + colbase + lr];
        const float qv1 = query[b * EE + colbase + 16 + lr];
        __syncthreads();
        #pragma unroll
        for (int mt = 0; mt < 2; ++mt)
            #pragma unroll
            for (int reg = 0; reg < 4; ++reg) {
                float p = (acc2[mt][0][reg] + b2v[0]) * qv0
                        + (acc2[mt][1][reg] + b2v[1]) * qv1;
                p += __shfl_xor(p, 1, 64);
                p += __shfl_xor(p, 2, 64);
                p += __shfl_xor(p, 4, 64);
                p += __shfl_xor(p, 8, 64);
                if (lr == 0) plog[(mt * 16 + lk * 4 + reg) * 4 + w] = p;
            }
        __syncthreads();
        if (tid < 32) {
            const float l = plog[tid * 4] + plog[tid * 4 + 1] + plog[tid * 4 + 2] + plog[tid * 4 + 3];
            lbuf0[row0 + tid] = l * gp[row0 + tid];
        }
    } else {
        __bf16* out = mout + (size_t)(hop - 1) * 32768 * EE;
        #pragma unroll
        for (int mt = 0; mt < 2; ++mt)
            #pragma unroll
            for (int nt = 0; nt < 2; ++nt)
                #pragma unroll
                for (int reg = 0; reg < 4; ++reg) {
                    const int rg_ = row0 + mt * 16 + lk * 4 + reg;
                    out[(size_t)rg_ * EE + colbase + nt * 16 + lr] =
                        (__bf16)(acc2[mt][nt][reg] + b2v[nt]);
                }
    }
}

// ---------------------------------------------------------------------------
// Grid barrier (agent scope). Safe: 256 blocks, ~37 KB LDS -> 4 blocks/CU ->
// capacity 1024 >> 256, all blocks resident regardless of placement.
// ---------------------------------------------------------------------------
static __device__ inline void gridbar(unsigned* cnt, unsigned* gen,
                                      unsigned target, int tid)
{
    __syncthreads();
    if (tid == 0) {
        __threadfence();   // agent-scope release of prior global writes
        const unsigned arr =
            __hip_atomic_fetch_add(cnt, 1u, __ATOMIC_ACQ_REL, __HIP_MEMORY_SCOPE_AGENT) + 1;
        if (arr == NTB) {
            __hip_atomic_store(cnt, 0u, __ATOMIC_RELAXED, __HIP_MEMORY_SCOPE_AGENT);
            __hip_atomic_fetch_add(gen, 1u, __ATOMIC_ACQ_REL, __HIP_MEMORY_SCOPE_AGENT);
        } else {
            while (__hip_atomic_load(gen, __ATOMIC_ACQUIRE, __HIP_MEMORY_SCOPE_AGENT) < target) {
                __builtin_amdgcn_s_sleep(1);
            }
        }
    }
    __syncthreads();
}

// ---------------------------------------------------------------------------
// tail_coop: whole 3-hop attention, ONE wide dispatch. 256 blocks x 256 thr.
// Block (b, seg) owns rows [seg*128, seg*128+128) of batch b; m-rows loaded
// into LDS once per hop and reused for update AND logits.
// ---------------------------------------------------------------------------
__global__ __launch_bounds__(256)
void tail_coop(const __bf16* __restrict__ m, const float* __restrict__ gp,
               const float* __restrict__ lbuf0, float* __restrict__ lbuf1,
               float* __restrict__ uqA, float* __restrict__ uqB,
               unsigned* __restrict__ syncv,
               float* __restrict__ out_logits, float* __restrict__ out_soft)
{
    __shared__ __bf16 Ms[128 * MS_STRIDE];   // 34,816 B
    __shared__ float uqs[128];
    __shared__ float wls[128];
    __shared__ float redm[4], reds[4];
    __shared__ float part[4][128];

    unsigned* cnt = syncv;
    unsigned* gen = syncv + 1;

    const int b    = blockIdx.x >> 4;
    const int seg  = blockIdx.x & 15;
    const int rlo  = seg * 128;
    const int tid  = threadIdx.x;
    const int w    = tid >> 6;
    const int lane = tid & 63;
    const int g    = lane >> 4;
    const int l16  = lane & 15;
    const float* gpb = gp + (size_t)b * MM;

    float mx, inv;

    // ===== stats helper expanded inline (over a 2048-float row) =====
    #define STATS2048(LB)                                                      \
        {                                                                      \
            float v_[8]; float m_ = -1e30f;                                    \
            _Pragma("unroll")                                                  \
            for (int i_ = 0; i_ < 8; ++i_) {                                   \
                v_[i_] = (LB)[i_ * 256 + tid]; m_ = fmaxf(m_, v_[i_]);         \
            }                                                                  \
            _Pragma("unroll")                                                  \
            for (int o_ = 32; o_ > 0; o_ >>= 1)                                \
                m_ = fmaxf(m_, __shfl_xor(m_, o_, 64));                        \
            if (lane == 0) redm[w] = m_;                                       \
            __syncthreads();                                                   \
            mx = fmaxf(fmaxf(redm[0], redm[1]), fmaxf(redm[2], redm[3]));      \
            float s_ = 0.f;                                                    \
            _Pragma("unroll")                                                  \
            for (int i_ = 0; i_ < 8; ++i_) s_ += __expf(v_[i_] - mx);          \
            _Pragma("unroll")                                                  \
            for (int o_ = 32; o_ > 0; o_ >>= 1) s_ += __shfl_xor(s_, o_, 64);  \
            if (lane == 0) reds[w] = s_;                                       \
            __syncthreads();                                                   \
            inv = 1.f / (reds[0] + reds[1] + reds[2] + reds[3]);               \
        }

    #define LOAD_MS(HOPIDX)                                                    \
        {                                                                      \
            const __bf16* mb_ = m + ((size_t)(HOPIDX) * (BB * MM)              \
                                     + (size_t)b * MM + rlo) * EE;             \
            for (int i_ = tid; i_ < 128 * 16; i_ += 256) {                     \
                const int r_ = i_ >> 4, c_ = (i_ & 15) * 8;                    \
                *(bf16x8*)&Ms[r_ * MS_STRIDE + c_] =                           \
                    *(const bf16x8*)&mb_[(size_t)r_ * EE + c_];                \
            }                                                                  \
        }

    #define UPDATE_PHASE(UQ)                                                   \
        {                                                                      \
            float acc_[8];                                                     \
            _Pragma("unroll")                                                  \
            for (int q_ = 0; q_ < 8; ++q_) acc_[q_] = 0.f;                     \
            _Pragma("unroll")                                                  \
            for (int it_ = 0; it_ < 8; ++it_) {                                \
                const int row_ = w * 32 + it_ * 4 + g;                         \
                const float wg_ = wls[row_];                                   \
                const bf16x8 mv_ = *(const bf16x8*)&Ms[row_ * MS_STRIDE + l16 * 8]; \
                _Pragma("unroll")                                              \
                for (int q_ = 0; q_ < 8; ++q_) acc_[q_] += wg_ * (float)mv_[q_]; \
            }                                                                  \
            _Pragma("unroll")                                                  \
            for (int q_ = 0; q_ < 8; ++q_) {                                   \
                acc_[q_] += __shfl_xor(acc_[q_], 16, 64);                      \
                acc_[q_] += __shfl_xor(acc_[q_], 32, 64);                      \
            }                                                                  \
            if (lane < 16) {                                                   \
                _Pragma("unroll")                                              \
                for (int q_ = 0; q_ < 8; ++q_) part[w][l16 * 8 + q_] = acc_[q_]; \
            }                                                                  \
            __syncthreads();                                                   \
            if (tid < 128) {                                                   \
                const float s_ = part[0][tid] + part[1][tid]                   \
                               + part[2][tid] + part[3][tid];                  \
                atomicAdd(&(UQ)[b * EE + tid], s_);                            \
            }                                                                  \
        }

    #define LOGITS_PHASE(DST)                                                  \
        {                                                                      \
            float u_[8];                                                       \
            _Pragma("unroll")                                                  \
            for (int j_ = 0; j_ < 8; ++j_) u_[j_] = uqs[l16 * 8 + j_];         \
            _Pragma("unroll")                                                  \
            for (int it_ = 0; it_ < 8; ++it_) {                                \
                const int row_ = w * 32 + it_ * 4 + g;                         \
                const bf16x8 mv_ = *(const bf16x8*)&Ms[row_ * MS_STRIDE + l16 * 8]; \
                float p_ = 0.f;                                                \
                _Pragma("unroll")                                              \
                for (int j_ = 0; j_ < 8; ++j_) p_ += (float)mv_[j_] * u_[j_];  \
                p_ += __shfl_xor(p_, 1, 64);                                   \
                p_ += __shfl_xor(p_, 2, 64);                                   \
                p_ += __shfl_xor(p_, 4, 64);                                   \
                p_ += __shfl_xor(p_, 8, 64);                                   \
                if (l16 == 0)                                                  \
                    (DST)[(size_t)b * MM + rlo + row_] = p_ * gpb[rlo + row_]; \
            }                                                                  \
        }

    // ---- Phase A: softmax0 stats + update1 -> uqA (init'd to query) ----
    LOAD_MS(0);
    STATS2048(lbuf0 + (size_t)b * MM);
    if (tid < 128)
        wls[tid] = __expf(lbuf0[(size_t)b * MM + rlo + tid] - mx) * inv * gpb[rlo + tid];
    __syncthreads();
    UPDATE_PHASE(uqA);
    gridbar(cnt, gen, 1, tid);

    // ---- Phase B: logits1 -> lbuf1 ----
    if (tid < 128) uqs[tid] = uqA[b * EE + tid];
    __syncthreads();
    LOGITS_PHASE(lbuf1);
    gridbar(cnt, gen, 2, tid);

    // ---- Phase C: softmax1 stats + update2 -> uqB (init'd to 0) ----
    LOAD_MS(1);
    STATS2048(lbuf1 + (size_t)b * MM);
    if (tid < 128)
        wls[tid] = __expf(lbuf1[(size_t)b * MM + rlo + tid] - mx) * inv * gpb[rlo + tid];
    __syncthreads();
    UPDATE_PHASE(uqB);
    gridbar(cnt, gen, 3, tid);

    // ---- Phase D: logits2 -> out_logits ----
    if (tid < 128) uqs[tid] = uqA[b * EE + tid] + uqB[b * EE + tid];
    __syncthreads();
    LOGITS_PHASE(out_logits);
    gridbar(cnt, gen, 4, tid);

    // ---- Phase E: softmax2 -> out_soft ----
    STATS2048(out_logits + (size_t)b * MM);
    if (tid < 128) {
        const int r = rlo + tid;
        out_soft[(size_t)b * MM + r] =
            __expf(out_logits[(size_t)b * MM + r] - mx) * inv;
    }
    #undef STATS2048
    #undef LOAD_MS
    #undef UPDATE_PHASE
    #undef LOGITS_PHASE
}

// ---------------------------------------------------------------------------
extern "C" void kernel_launch(void* const* d_in, const int* in_sizes, int n_in,
                              void* d_out, int out_size, void* d_ws, size_t ws_size,
                              hipStream_t stream) {
    const int*   story    = (const int*)d_in[0];
    const int*   kb_len   = (const int*)d_in[1];
    const int*   conv_len = (const int*)d_in[2];
    // d_in[3] = hidden (dead w.r.t. outputs)
    const float* dh       = (const float*)d_in[4];
    const float* tf       = (const float*)d_in[5];
    const float* query    = (const float*)d_in[6];
    const float* gp       = (const float*)d_in[7];
    const float* C        = (const float*)d_in[8];
    const float* wA1      = (const float*)d_in[9];
    const float* bA1      = (const float*)d_in[10];
    const float* wA2      = (const float*)d_in[11];
    const float* bA2      = (const float*)d_in[12];
    // wC1/bC1/wC2/bC2, wf/bf: dead w.r.t. outputs

    char* ws = (char*)d_ws;
    const size_t M_ELEMS = (size_t)32768 * EE;
    size_t off = 0;
    __bf16* m   = (__bf16*)(ws + off); off += 2 * M_ELEMS * sizeof(__bf16);    // eA1, eA2
    __bf16* Cb  = (__bf16*)(ws + off); off += (size_t)3 * VV * EE * sizeof(__bf16);
    __bf16* dhb = (__bf16*)(ws + off); off += (size_t)BB * LCC * EE * sizeof(__bf16);
    __bf16* tfb = (__bf16*)(ws + off); off += (size_t)BB * EE * sizeof(__bf16);
    __bf16* w1t = (__bf16*)(ws + off); off += 256 * 128 * sizeof(__bf16);
    __bf16* w2t = (__bf16*)(ws + off); off += 128 * 128 * sizeof(__bf16);
    float* lbuf0 = (float*)(ws + off); off += (size_t)BB * MM * sizeof(float);
    float* lbuf1 = (float*)(ws + off); off += (size_t)BB * MM * sizeof(float);
    float* uqA   = (float*)(ws + off); off += (size_t)BB * EE * sizeof(float);
    float* uqB   = (float*)(ws + off); off += (size_t)BB * EE * sizeof(float);
    unsigned* syncv = (unsigned*)(ws + off); off += 64;

    float* out_soft   = (float*)d_out;
    float* out_logits = out_soft + (size_t)BB * MM;

    megaprep<<<(N_PREP + 255) / 256, 256, 0, stream>>>(C, dh, tf, wA1, wA2, query,
                                                       Cb, dhb, tfb, w1t, w2t,
                                                       uqA, uqB, syncv);
    embed_mlp_mfma<<<3072, 256, 0, stream>>>(story, kb_len, conv_len, Cb, dhb, tfb,
                                             w1t, bA1, w2t, bA2, gp, query, m, lbuf0);
    tail_coop<<<NTB, 256, 0, stream>>>(m, gp, lbuf0, lbuf1, uqA, uqB, syncv,
                                       out_logits, out_soft);
}

// Round 7
// 197.703 us; speedup vs baseline: 1.4555x; 1.4555x over previous
//
#include <hip/hip_runtime.h>
#include <math.h>

#define BB 16
#define MM 2048
#define SS 6
#define EE 128
#define LCC 512
#define VV 32000

typedef __attribute__((ext_vector_type(8))) __bf16 bf16x8;
typedef __attribute__((ext_vector_type(4))) float f32x4;

#define XS_STRIDE 264   // 256+8 bf16 pad
#define HS_STRIDE 136   // 128+8 bf16 pad

static __device__ inline unsigned short bfbits(float x) {
    __bf16 h = (__bf16)x;
    return __builtin_bit_cast(unsigned short, h);
}

// ---------------------------------------------------------------------------
// prep_small: W1/W2 fp32 -> bf16 transposed [n][k]; uqA = uqB = 0.
// Tiny (~0.3 MB) — replaces the heavy megaprep (C stays fp32, gathered direct).
// ---------------------------------------------------------------------------
#define N_W1  (256 * 128)              // 32,768
#define N_W2  (128 * 128)              // 16,384
#define N_UQ  (BB * EE)                // 2,048
#define N_PREP (N_W1 + N_W2 + 2 * N_UQ)   // 53,248 = 208*256

__global__ __launch_bounds__(256)
void prep_small(const float* __restrict__ W1, const float* __restrict__ W2,
                __bf16* __restrict__ w1t, __bf16* __restrict__ w2t,
                float* __restrict__ uqA, float* __restrict__ uqB)
{
    int i = blockIdx.x * 256 + threadIdx.x;
    if (i < N_W1) { const int n = i >> 8, k = i & 255; w1t[i] = (__bf16)W1[k * EE + n]; return; }
    i -= N_W1;
    if (i < N_W2) { const int n = i >> 7, k = i & 127; w2t[i] = (__bf16)W2[k * EE + n]; return; }
    i -= N_W2;
    if (i < N_UQ) { uqA[i] = 0.f; return; }
    i -= N_UQ;
    if (i < N_UQ) { uqB[i] = 0.f; }
}

// ---------------------------------------------------------------------------
// Fused embed gather-sum (fp32 C, direct) + add_lm + MFMA MLP, 3 hops.
// hop 0: logits0 in-register (Y . query), m0 never stored. hops 1,2: -> mout.
// 3072 blocks x 32 rows, 256 threads = 4 waves.
// ---------------------------------------------------------------------------
__global__ __launch_bounds__(256)
void embed_mlp_mfma(const int* __restrict__ story,
                    const int* __restrict__ kb_len,
                    const int* __restrict__ conv_len,
                    const float* __restrict__ dh,
                    const float* __restrict__ tf,
                    const float* __restrict__ C,
                    const __bf16* __restrict__ w1t, const float* __restrict__ b1,
                    const __bf16* __restrict__ w2t, const float* __restrict__ b2,
                    const float* __restrict__ gp, const float* __restrict__ query,
                    __bf16* __restrict__ mout, float* __restrict__ lbuf0)
{
    __shared__ __bf16 Xs[32 * XS_STRIDE];   // 16,896 B
    __shared__ __bf16 Hs[32 * HS_STRIDE];   //  8,704 B
    __shared__ int    sidx[32 * SS];
    float* plog = (float*)Hs;               // aliases Hs after GEMM2 reads

    const int bid  = blockIdx.x;
    const int hop  = bid >> 10;
    const int row0 = (bid & 1023) * 32;
    const int b    = row0 >> 11;
    const int tid  = threadIdx.x;

    const float* Ck = C + (size_t)hop * VV * EE;

    for (int i = tid; i < 32 * SS; i += 256) sidx[i] = story[(size_t)row0 * SS + i];

    const int kb   = kb_len[b];
    const int cl   = conv_len[b];
    const int rgrp = tid >> 5;              // 0..7
    const int e4   = (tid & 31) * 4;        // 4-float col group
    const float4 tf4 = *(const float4*)&tf[b * EE + e4];
    ushort4 tfp;
    tfp.x = bfbits(tf4.x); tfp.y = bfbits(tf4.y); tfp.z = bfbits(tf4.z); tfp.w = bfbits(tf4.w);
    __syncthreads();

    // ---- gather X: fp32 float4 reads, packed bf16x4 LDS stores ----
    for (int chunk = 0; chunk < 4; ++chunk) {
        const int r  = chunk * 8 + rgrp;
        const int* si = &sidx[r * SS];
        float4 v[SS];
        #pragma unroll
        for (int s = 0; s < SS; ++s)
            v[s] = *(const float4*)&Ck[(size_t)si[s] * EE + e4];
        const int j = ((row0 + r) & (MM - 1)) - kb;
        float4 acc = {0.f, 0.f, 0.f, 0.f};
        if (j >= 0 && j < cl)
            acc = *(const float4*)&dh[((size_t)b * LCC + j) * EE + e4];
        #pragma unroll
        for (int s = 0; s < SS; ++s) {
            acc.x += v[s].x; acc.y += v[s].y; acc.z += v[s].z; acc.w += v[s].w;
        }
        ushort4 pk;
        pk.x = bfbits(acc.x); pk.y = bfbits(acc.y); pk.z = bfbits(acc.z); pk.w = bfbits(acc.w);
        *(ushort4*)&Xs[r * XS_STRIDE + e4]      = pk;
        *(ushort4*)&Xs[r * XS_STRIDE + EE + e4] = tfp;
    }
    __syncthreads();

    const int w       = tid >> 6;
    const int lane    = tid & 63;
    const int lr      = lane & 15;
    const int lk      = lane >> 4;
    const int colbase = w * 32;

    // ---- GEMM1: H = lrelu(X @ W1 + b1) ----
    f32x4 acc1[2][2];
    #pragma unroll
    for (int i = 0; i < 2; ++i)
        #pragma unroll
        for (int j = 0; j < 2; ++j) acc1[i][j] = (f32x4){0.f, 0.f, 0.f, 0.f};

    for (int ks = 0; ks < 8; ++ks) {
        bf16x8 a[2], bw[2];
        #pragma unroll
        for (int mt = 0; mt < 2; ++mt)
            a[mt] = *(const bf16x8*)&Xs[(mt * 16 + lr) * XS_STRIDE + ks * 32 + lk * 8];
        #pragma unroll
        for (int nt = 0; nt < 2; ++nt)
            bw[nt] = *(const bf16x8*)&w1t[(size_t)(colbase + nt * 16 + lr) * 256 + ks * 32 + lk * 8];
        #pragma unroll
        for (int mt = 0; mt < 2; ++mt)
            #pragma unroll
            for (int nt = 0; nt < 2; ++nt)
                acc1[mt][nt] = __builtin_amdgcn_mfma_f32_16x16x32_bf16(a[mt], bw[nt], acc1[mt][nt], 0, 0, 0);
    }
    {
        const float b1v[2] = { b1[colbase + lr], b1[colbase + 16 + lr] };
        #pragma unroll
        for (int mt = 0; mt < 2; ++mt)
            #pragma unroll
            for (int nt = 0; nt < 2; ++nt)
                #pragma unroll
                for (int reg = 0; reg < 4; ++reg) {
                    float h = acc1[mt][nt][reg] + b1v[nt];
                    h = (h > 0.f) ? h : 0.1f * h;
                    Hs[(mt * 16 + lk * 4 + reg) * HS_STRIDE + colbase + nt * 16 + lr] = (__bf16)h;
                }
    }
    __syncthreads();

    // ---- GEMM2: Y = H @ W2 + b2 ----
    f32x4 acc2[2][2];
    #pragma unroll
    for (int i = 0; i < 2; ++i)
        #pragma unroll
        for (int j = 0; j < 2; ++j) acc2[i][j] = (f32x4){0.f, 0.f, 0.f, 0.f};

    for (int ks = 0; ks < 4; ++ks) {
        bf16x8 a[2], bw[2];
        #pragma unroll
        for (int mt = 0; mt < 2; ++mt)
            a[mt] = *(const bf16x8*)&Hs[(mt * 16 + lr) * HS_STRIDE + ks * 32 + lk * 8];
        #pragma unroll
        for (int nt = 0; nt < 2; ++nt)
            bw[nt] = *(const bf16x8*)&w2t[(size_t)(colbase + nt * 16 + lr) * 128 + ks * 32 + lk * 8];
        #pragma unroll
        for (int mt = 0; mt < 2; ++mt)
            #pragma unroll
            for (int nt = 0; nt < 2; ++nt)
                acc2[mt][nt] = __builtin_amdgcn_mfma_f32_16x16x32_bf16(a[mt], bw[nt], acc2[mt][nt], 0, 0, 0);
    }

    const float b2v[2] = { b2[colbase + lr], b2[colbase + 16 + lr] };

    if (hop == 0) {
        const float qv0 = query[b * EE + colbase + lr];
        const float qv1 = query[b * EE + colbase + 16 + lr];
        __syncthreads();    // Hs reads done; reuse as plog
        #pragma unroll
        for (int mt = 0; mt < 2; ++mt)
            #pragma unroll
            for (int reg = 0; reg < 4; ++reg) {
                float p = (acc2[mt][0][reg] + b2v[0]) * qv0
                        + (acc2[mt][1][reg] + b2v[1]) * qv1;
                p += __shfl_xor(p, 1, 64);
                p += __shfl_xor(p, 2, 64);
                p += __shfl_xor(p, 4, 64);
                p += __shfl_xor(p, 8, 64);
                if (lr == 0) plog[(mt * 16 + lk * 4 + reg) * 4 + w] = p;
            }
        __syncthreads();
        if (tid < 32) {
            const float l = plog[tid * 4] + plog[tid * 4 + 1] + plog[tid * 4 + 2] + plog[tid * 4 + 3];
            lbuf0[row0 + tid] = l * gp[row0 + tid];
        }
    } else {
        __bf16* out = mout + (size_t)(hop - 1) * 32768 * EE;
        #pragma unroll
        for (int mt = 0; mt < 2; ++mt)
            #pragma unroll
            for (int nt = 0; nt < 2; ++nt)
                #pragma unroll
                for (int reg = 0; reg < 4; ++reg) {
                    const int rg_ = row0 + mt * 16 + lk * 4 + reg;
                    out[(size_t)rg_ * EE + colbase + nt * 16 + lr] =
                        (__bf16)(acc2[mt][nt][reg] + b2v[nt]);
                }
    }
}

// ---------------------------------------------------------------------------
// update: inline softmax of lbuf[b,:] (recomputed per block), then
// uq[b,:] += sum over 64 rows of gp*soft * mk[row,:].  512 blocks x 256.
// ---------------------------------------------------------------------------
__global__ __launch_bounds__(256)
void update_kernel(const __bf16* __restrict__ mk, const float* __restrict__ gp,
                   const float* __restrict__ lbuf, float* __restrict__ uq)
{
    __shared__ float redm[4], reds[4];
    __shared__ float wls[64];
    __shared__ float part[4][128];

    const int b      = blockIdx.x >> 5;
    const int rloc0  = (blockIdx.x & 31) * 64;
    const int tid    = threadIdx.x;
    const int lane   = tid & 63;
    const int w      = tid >> 6;
    const float* lb  = lbuf + (size_t)b * MM;

    float v[8];
    float mx = -1e30f;
    #pragma unroll
    for (int i = 0; i < 8; ++i) { v[i] = lb[i * 256 + tid]; mx = fmaxf(mx, v[i]); }
    #pragma unroll
    for (int off = 32; off > 0; off >>= 1) mx = fmaxf(mx, __shfl_xor(mx, off, 64));
    if (lane == 0) redm[w] = mx;
    __syncthreads();
    mx = fmaxf(fmaxf(redm[0], redm[1]), fmaxf(redm[2], redm[3]));
    float sum = 0.f;
    #pragma unroll
    for (int i = 0; i < 8; ++i) sum += __expf(v[i] - mx);
    #pragma unroll
    for (int off = 32; off > 0; off >>= 1) sum += __shfl_xor(sum, off, 64);
    if (lane == 0) reds[w] = sum;
    __syncthreads();
    const float inv = 1.f / (reds[0] + reds[1] + reds[2] + reds[3]);

    if (tid < 64)
        wls[tid] = gp[(size_t)b * MM + rloc0 + tid] * __expf(lb[rloc0 + tid] - mx) * inv;
    __syncthreads();

    const int rgrp = tid >> 4;
    const int e8   = (tid & 15) * 8;
    float acc[8];
    #pragma unroll
    for (int q = 0; q < 8; ++q) acc[q] = 0.f;
    #pragma unroll
    for (int p = 0; p < 4; ++p) {
        const int rl  = p * 16 + rgrp;
        const float wg = wls[rl];
        const bf16x8 vv = *(const bf16x8*)&mk[((size_t)b * MM + rloc0 + rl) * EE + e8];
        #pragma unroll
        for (int q = 0; q < 8; ++q) acc[q] += wg * (float)vv[q];
    }
    #pragma unroll
    for (int q = 0; q < 8; ++q) {
        acc[q] += __shfl_xor(acc[q], 16, 64);
        acc[q] += __shfl_xor(acc[q], 32, 64);
    }
    if (lane < 16) {
        #pragma unroll
        for (int q = 0; q < 8; ++q) part[w][e8 + q] = acc[q];
    }
    __syncthreads();
    if (tid < 128) {
        const float s = part[0][tid] + part[1][tid] + part[2][tid] + part[3][tid];
        atomicAdd(&uq[b * EE + tid], s);
    }
}

// ---------------------------------------------------------------------------
// logits[row] = gp[row] * dot(mk[row,:], query[b]+uqa[b](+uqb[b])).
// 512 blocks x 64 rows.
// ---------------------------------------------------------------------------
__global__ __launch_bounds__(256)
void logits_kernel(const __bf16* __restrict__ mk, const float* __restrict__ gp,
                   const float* __restrict__ query, const float* __restrict__ uqa,
                   const float* __restrict__ uqb, float* __restrict__ out)
{
    __shared__ float uqs[128];
    const int row0 = blockIdx.x * 64;
    const int b    = row0 >> 11;
    const int tid  = threadIdx.x;
    if (tid < 128)
        uqs[tid] = query[b * EE + tid] + uqa[b * EE + tid]
                 + (uqb ? uqb[b * EE + tid] : 0.f);
    __syncthreads();
    const int w = tid >> 6, lane = tid & 63;
    const int g = lane >> 4, l16 = lane & 15;
    float u[8];
    #pragma unroll
    for (int j = 0; j < 8; ++j) u[j] = uqs[l16 * 8 + j];
    #pragma unroll
    for (int it = 0; it < 4; ++it) {
        const int row = row0 + it * 16 + w * 4 + g;
        const bf16x8 v = *(const bf16x8*)&mk[(size_t)row * EE + l16 * 8];
        float p = 0.f;
        #pragma unroll
        for (int j = 0; j < 8; ++j) p += (float)v[j] * u[j];
        p += __shfl_xor(p, 1, 64);
        p += __shfl_xor(p, 2, 64);
        p += __shfl_xor(p, 4, 64);
        p += __shfl_xor(p, 8, 64);
        if (l16 == 0) out[row] = p * gp[row];
    }
}

// ---------------------------------------------------------------------------
// final softmax: block per b.
// ---------------------------------------------------------------------------
__global__ __launch_bounds__(256)
void softmax_final(const float* __restrict__ logits, float* __restrict__ soft)
{
    __shared__ float redm[4], reds[4];
    const int b = blockIdx.x, tid = threadIdx.x;
    const int lane = tid & 63, w = tid >> 6;
    const float* lb = logits + (size_t)b * MM;
    float v[8];
    float mx = -1e30f;
    #pragma unroll
    for (int i = 0; i < 8; ++i) { v[i] = lb[i * 256 + tid]; mx = fmaxf(mx, v[i]); }
    #pragma unroll
    for (int off = 32; off > 0; off >>= 1) mx = fmaxf(mx, __shfl_xor(mx, off, 64));
    if (lane == 0) redm[w] = mx;
    __syncthreads();
    mx = fmaxf(fmaxf(redm[0], redm[1]), fmaxf(redm[2], redm[3]));
    float sum = 0.f;
    #pragma unroll
    for (int i = 0; i < 8; ++i) { v[i] = __expf(v[i] - mx); sum += v[i]; }
    #pragma unroll
    for (int off = 32; off > 0; off >>= 1) sum += __shfl_xor(sum, off, 64);
    if (lane == 0) reds[w] = sum;
    __syncthreads();
    const float inv = 1.f / (reds[0] + reds[1] + reds[2] + reds[3]);
    #pragma unroll
    for (int i = 0; i < 8; ++i) soft[(size_t)b * MM + i * 256 + tid] = v[i] * inv;
}

// ---------------------------------------------------------------------------
extern "C" void kernel_launch(void* const* d_in, const int* in_sizes, int n_in,
                              void* d_out, int out_size, void* d_ws, size_t ws_size,
                              hipStream_t stream) {
    const int*   story    = (const int*)d_in[0];
    const int*   kb_len   = (const int*)d_in[1];
    const int*   conv_len = (const int*)d_in[2];
    // d_in[3] = hidden (dead w.r.t. outputs)
    const float* dh       = (const float*)d_in[4];
    const float* tf       = (const float*)d_in[5];
    const float* query    = (const float*)d_in[6];
    const float* gp       = (const float*)d_in[7];
    const float* C        = (const float*)d_in[8];
    const float* wA1      = (const float*)d_in[9];
    const float* bA1      = (const float*)d_in[10];
    const float* wA2      = (const float*)d_in[11];
    const float* bA2      = (const float*)d_in[12];
    // wC1/bC1/wC2/bC2, wf/bf: dead w.r.t. outputs

    char* ws = (char*)d_ws;
    const size_t M_ELEMS = (size_t)32768 * EE;
    size_t off = 0;
    __bf16* m   = (__bf16*)(ws + off); off += 2 * M_ELEMS * sizeof(__bf16);    // m1, m2
    __bf16* w1t = (__bf16*)(ws + off); off += 256 * 128 * sizeof(__bf16);
    __bf16* w2t = (__bf16*)(ws + off); off += 128 * 128 * sizeof(__bf16);
    float* lbuf = (float*)(ws + off);  off += (size_t)BB * MM * sizeof(float);
    float* uqA  = (float*)(ws + off);  off += (size_t)BB * EE * sizeof(float);
    float* uqB  = (float*)(ws + off);  off += (size_t)BB * EE * sizeof(float);

    float* out_soft   = (float*)d_out;
    float* out_logits = out_soft + (size_t)BB * MM;

    prep_small<<<N_PREP / 256, 256, 0, stream>>>(wA1, wA2, w1t, w2t, uqA, uqB);
    embed_mlp_mfma<<<3072, 256, 0, stream>>>(story, kb_len, conv_len, dh, tf, C,
                                             w1t, bA1, w2t, bA2, gp, query, m, lbuf);
    // hop1: uqA = m1^T(gp*soft0);  logits1 = gp*(m1 (query+uqA)) -> lbuf
    update_kernel<<<512, 256, 0, stream>>>(m, gp, lbuf, uqA);
    logits_kernel<<<512, 256, 0, stream>>>(m, gp, query, uqA, nullptr, lbuf);
    // hop2: uqB = m2^T(gp*soft1);  logits2 = gp*(m2 (query+uqA+uqB)) -> out
    update_kernel<<<512, 256, 0, stream>>>(m + M_ELEMS, gp, lbuf, uqB);
    logits_kernel<<<512, 256, 0, stream>>>(m + M_ELEMS, gp, query, uqA, uqB, out_logits);
    softmax_final<<<BB, 256, 0, stream>>>(out_logits, out_soft);
}

// Round 8
// 194.459 us; speedup vs baseline: 1.4798x; 1.0167x over previous
//
#include <hip/hip_runtime.h>
#include <math.h>

#define BB 16
#define MM 2048
#define SS 6
#define EE 128
#define LCC 512
#define VV 32000

typedef __attribute__((ext_vector_type(8))) __bf16 bf16x8;
typedef __attribute__((ext_vector_type(4))) float f32x4;

#define XS_STRIDE 264   // 256+8 bf16 pad
#define HS_STRIDE 136   // 128+8 bf16 pad

static __device__ inline unsigned short bfbits(float x) {
    __bf16 h = (__bf16)x;
    return __builtin_bit_cast(unsigned short, h);
}

// ---------------------------------------------------------------------------
// prep_small: W1/W2 fp32 -> bf16 transposed [n][k]; uqA = uqB = 0.
// ---------------------------------------------------------------------------
#define N_W1  (256 * 128)              // 32,768
#define N_W2  (128 * 128)              // 16,384
#define N_UQ  (BB * EE)                // 2,048
#define N_PREP (N_W1 + N_W2 + 2 * N_UQ)   // 53,248 = 208*256

__global__ __launch_bounds__(256)
void prep_small(const float* __restrict__ W1, const float* __restrict__ W2,
                __bf16* __restrict__ w1t, __bf16* __restrict__ w2t,
                float* __restrict__ uqA, float* __restrict__ uqB)
{
    int i = blockIdx.x * 256 + threadIdx.x;
    if (i < N_W1) { const int n = i >> 8, k = i & 255; w1t[i] = (__bf16)W1[k * EE + n]; return; }
    i -= N_W1;
    if (i < N_W2) { const int n = i >> 7, k = i & 127; w2t[i] = (__bf16)W2[k * EE + n]; return; }
    i -= N_W2;
    if (i < N_UQ) { uqA[i] = 0.f; return; }
    i -= N_UQ;
    if (i < N_UQ) { uqB[i] = 0.f; }
}

// ---------------------------------------------------------------------------
// Fused embed gather-sum (fp32 C, direct) + add_lm + MFMA MLP, 3 hops.
// hop 0: logits0 in-register, m0 never stored. hops 1,2: Y -> mout bf16.
// LDS: Hs/plog ALIAS Xs (Xs dead after GEMM1 K-loop; barrier-separated).
// 17.7 KB LDS -> 8 blocks/CU (wave cap) vs 6 before — occupancy 36% -> ~70%.
// ---------------------------------------------------------------------------
__global__ __launch_bounds__(256)
void embed_mlp_mfma(const int* __restrict__ story,
                    const int* __restrict__ kb_len,
                    const int* __restrict__ conv_len,
                    const float* __restrict__ dh,
                    const float* __restrict__ tf,
                    const float* __restrict__ C,
                    const __bf16* __restrict__ w1t, const float* __restrict__ b1,
                    const __bf16* __restrict__ w2t, const float* __restrict__ b2,
                    const float* __restrict__ gp, const float* __restrict__ query,
                    __bf16* __restrict__ mout, float* __restrict__ lbuf0)
{
    __shared__ __bf16 Xs[32 * XS_STRIDE];   // 16,896 B; Hs (8,704 B) aliases
    __shared__ int    sidx[32 * SS];
    __bf16* Hs   = Xs;                      // valid: Xs dead before H written
    float*  plog = (float*)Xs;              // valid: Hs dead before plog written

    const int bid  = blockIdx.x;
    const int hop  = bid >> 10;
    const int row0 = (bid & 1023) * 32;
    const int b    = row0 >> 11;
    const int tid  = threadIdx.x;

    const float* Ck = C + (size_t)hop * VV * EE;

    for (int i = tid; i < 32 * SS; i += 256) sidx[i] = story[(size_t)row0 * SS + i];

    const int kb   = kb_len[b];
    const int cl   = conv_len[b];
    const int rgrp = tid >> 5;              // 0..7
    const int e4   = (tid & 31) * 4;        // 4-float col group
    const float4 tf4 = *(const float4*)&tf[b * EE + e4];
    ushort4 tfp;
    tfp.x = bfbits(tf4.x); tfp.y = bfbits(tf4.y); tfp.z = bfbits(tf4.z); tfp.w = bfbits(tf4.w);
    __syncthreads();

    // ---- gather X: fp32 float4 reads, packed bf16x4 LDS stores ----
    for (int chunk = 0; chunk < 4; ++chunk) {
        const int r  = chunk * 8 + rgrp;
        const int* si = &sidx[r * SS];
        float4 v[SS];
        #pragma unroll
        for (int s = 0; s < SS; ++s)
            v[s] = *(const float4*)&Ck[(size_t)si[s] * EE + e4];
        const int j = ((row0 + r) & (MM - 1)) - kb;
        float4 acc = {0.f, 0.f, 0.f, 0.f};
        if (j >= 0 && j < cl)
            acc = *(const float4*)&dh[((size_t)b * LCC + j) * EE + e4];
        #pragma unroll
        for (int s = 0; s < SS; ++s) {
            acc.x += v[s].x; acc.y += v[s].y; acc.z += v[s].z; acc.w += v[s].w;
        }
        ushort4 pk;
        pk.x = bfbits(acc.x); pk.y = bfbits(acc.y); pk.z = bfbits(acc.z); pk.w = bfbits(acc.w);
        *(ushort4*)&Xs[r * XS_STRIDE + e4]      = pk;
        *(ushort4*)&Xs[r * XS_STRIDE + EE + e4] = tfp;
    }
    __syncthreads();

    const int w       = tid >> 6;
    const int lane    = tid & 63;
    const int lr      = lane & 15;
    const int lk      = lane >> 4;
    const int colbase = w * 32;

    // ---- GEMM1: H = lrelu(X @ W1 + b1) ----
    f32x4 acc1[2][2];
    #pragma unroll
    for (int i = 0; i < 2; ++i)
        #pragma unroll
        for (int j = 0; j < 2; ++j) acc1[i][j] = (f32x4){0.f, 0.f, 0.f, 0.f};

    for (int ks = 0; ks < 8; ++ks) {
        bf16x8 a[2], bw[2];
        #pragma unroll
        for (int mt = 0; mt < 2; ++mt)
            a[mt] = *(const bf16x8*)&Xs[(mt * 16 + lr) * XS_STRIDE + ks * 32 + lk * 8];
        #pragma unroll
        for (int nt = 0; nt < 2; ++nt)
            bw[nt] = *(const bf16x8*)&w1t[(size_t)(colbase + nt * 16 + lr) * 256 + ks * 32 + lk * 8];
        #pragma unroll
        for (int mt = 0; mt < 2; ++mt)
            #pragma unroll
            for (int nt = 0; nt < 2; ++nt)
                acc1[mt][nt] = __builtin_amdgcn_mfma_f32_16x16x32_bf16(a[mt], bw[nt], acc1[mt][nt], 0, 0, 0);
    }
    __syncthreads();   // all Xs reads complete before Hs (alias) is written
    {
        const float b1v[2] = { b1[colbase + lr], b1[colbase + 16 + lr] };
        #pragma unroll
        for (int mt = 0; mt < 2; ++mt)
            #pragma unroll
            for (int nt = 0; nt < 2; ++nt)
                #pragma unroll
                for (int reg = 0; reg < 4; ++reg) {
                    float h = acc1[mt][nt][reg] + b1v[nt];
                    h = (h > 0.f) ? h : 0.1f * h;
                    Hs[(mt * 16 + lk * 4 + reg) * HS_STRIDE + colbase + nt * 16 + lr] = (__bf16)h;
                }
    }
    __syncthreads();

    // ---- GEMM2: Y = H @ W2 + b2 ----
    f32x4 acc2[2][2];
    #pragma unroll
    for (int i = 0; i < 2; ++i)
        #pragma unroll
        for (int j = 0; j < 2; ++j) acc2[i][j] = (f32x4){0.f, 0.f, 0.f, 0.f};

    for (int ks = 0; ks < 4; ++ks) {
        bf16x8 a[2], bw[2];
        #pragma unroll
        for (int mt = 0; mt < 2; ++mt)
            a[mt] = *(const bf16x8*)&Hs[(mt * 16 + lr) * HS_STRIDE + ks * 32 + lk * 8];
        #pragma unroll
        for (int nt = 0; nt < 2; ++nt)
            bw[nt] = *(const bf16x8*)&w2t[(size_t)(colbase + nt * 16 + lr) * 128 + ks * 32 + lk * 8];
        #pragma unroll
        for (int mt = 0; mt < 2; ++mt)
            #pragma unroll
            for (int nt = 0; nt < 2; ++nt)
                acc2[mt][nt] = __builtin_amdgcn_mfma_f32_16x16x32_bf16(a[mt], bw[nt], acc2[mt][nt], 0, 0, 0);
    }

    const float b2v[2] = { b2[colbase + lr], b2[colbase + 16 + lr] };

    if (hop == 0) {
        const float qv0 = query[b * EE + colbase + lr];
        const float qv1 = query[b * EE + colbase + 16 + lr];
        __syncthreads();    // Hs reads done; reuse as plog
        #pragma unroll
        for (int mt = 0; mt < 2; ++mt)
            #pragma unroll
            for (int reg = 0; reg < 4; ++reg) {
                float p = (acc2[mt][0][reg] + b2v[0]) * qv0
                        + (acc2[mt][1][reg] + b2v[1]) * qv1;
                p += __shfl_xor(p, 1, 64);
                p += __shfl_xor(p, 2, 64);
                p += __shfl_xor(p, 4, 64);
                p += __shfl_xor(p, 8, 64);
                if (lr == 0) plog[(mt * 16 + lk * 4 + reg) * 4 + w] = p;
            }
        __syncthreads();
        if (tid < 32) {
            const float l = plog[tid * 4] + plog[tid * 4 + 1] + plog[tid * 4 + 2] + plog[tid * 4 + 3];
            lbuf0[row0 + tid] = l * gp[row0 + tid];
        }
    } else {
        __bf16* out = mout + (size_t)(hop - 1) * 32768 * EE;
        #pragma unroll
        for (int mt = 0; mt < 2; ++mt)
            #pragma unroll
            for (int nt = 0; nt < 2; ++nt)
                #pragma unroll
                for (int reg = 0; reg < 4; ++reg) {
                    const int rg_ = row0 + mt * 16 + lk * 4 + reg;
                    out[(size_t)rg_ * EE + colbase + nt * 16 + lr] =
                        (__bf16)(acc2[mt][nt][reg] + b2v[nt]);
                }
    }
}

// ---------------------------------------------------------------------------
// update: inline softmax of lbuf[b,:], then uq[b,:] += sum_{64 rows} gp*soft*mk.
// 512 blocks x 256.
// ---------------------------------------------------------------------------
__global__ __launch_bounds__(256)
void update_kernel(const __bf16* __restrict__ mk, const float* __restrict__ gp,
                   const float* __restrict__ lbuf, float* __restrict__ uq)
{
    __shared__ float redm[4], reds[4];
    __shared__ float wls[64];
    __shared__ float part[4][128];

    const int b      = blockIdx.x >> 5;
    const int rloc0  = (blockIdx.x & 31) * 64;
    const int tid    = threadIdx.x;
    const int lane   = tid & 63;
    const int w      = tid >> 6;
    const float* lb  = lbuf + (size_t)b * MM;

    float v[8];
    float mx = -1e30f;
    #pragma unroll
    for (int i = 0; i < 8; ++i) { v[i] = lb[i * 256 + tid]; mx = fmaxf(mx, v[i]); }
    #pragma unroll
    for (int off = 32; off > 0; off >>= 1) mx = fmaxf(mx, __shfl_xor(mx, off, 64));
    if (lane == 0) redm[w] = mx;
    __syncthreads();
    mx = fmaxf(fmaxf(redm[0], redm[1]), fmaxf(redm[2], redm[3]));
    float sum = 0.f;
    #pragma unroll
    for (int i = 0; i < 8; ++i) sum += __expf(v[i] - mx);
    #pragma unroll
    for (int off = 32; off > 0; off >>= 1) sum += __shfl_xor(sum, off, 64);
    if (lane == 0) reds[w] = sum;
    __syncthreads();
    const float inv = 1.f / (reds[0] + reds[1] + reds[2] + reds[3]);

    if (tid < 64)
        wls[tid] = gp[(size_t)b * MM + rloc0 + tid] * __expf(lb[rloc0 + tid] - mx) * inv;
    __syncthreads();

    const int rgrp = tid >> 4;
    const int e8   = (tid & 15) * 8;
    float acc[8];
    #pragma unroll
    for (int q = 0; q < 8; ++q) acc[q] = 0.f;
    #pragma unroll
    for (int p = 0; p < 4; ++p) {
        const int rl  = p * 16 + rgrp;
        const float wg = wls[rl];
        const bf16x8 vv = *(const bf16x8*)&mk[((size_t)b * MM + rloc0 + rl) * EE + e8];
        #pragma unroll
        for (int q = 0; q < 8; ++q) acc[q] += wg * (float)vv[q];
    }
    #pragma unroll
    for (int q = 0; q < 8; ++q) {
        acc[q] += __shfl_xor(acc[q], 16, 64);
        acc[q] += __shfl_xor(acc[q], 32, 64);
    }
    if (lane < 16) {
        #pragma unroll
        for (int q = 0; q < 8; ++q) part[w][e8 + q] = acc[q];
    }
    __syncthreads();
    if (tid < 128) {
        const float s = part[0][tid] + part[1][tid] + part[2][tid] + part[3][tid];
        atomicAdd(&uq[b * EE + tid], s);
    }
}

// ---------------------------------------------------------------------------
// logits[row] = gp[row] * dot(mk[row,:], query[b]+uqa[b](+uqb[b])).
// 512 blocks x 64 rows.
// ---------------------------------------------------------------------------
__global__ __launch_bounds__(256)
void logits_kernel(const __bf16* __restrict__ mk, const float* __restrict__ gp,
                   const float* __restrict__ query, const float* __restrict__ uqa,
                   const float* __restrict__ uqb, float* __restrict__ out)
{
    __shared__ float uqs[128];
    const int row0 = blockIdx.x * 64;
    const int b    = row0 >> 11;
    const int tid  = threadIdx.x;
    if (tid < 128)
        uqs[tid] = query[b * EE + tid] + uqa[b * EE + tid]
                 + (uqb ? uqb[b * EE + tid] : 0.f);
    __syncthreads();
    const int w = tid >> 6, lane = tid & 63;
    const int g = lane >> 4, l16 = lane & 15;
    float u[8];
    #pragma unroll
    for (int j = 0; j < 8; ++j) u[j] = uqs[l16 * 8 + j];
    #pragma unroll
    for (int it = 0; it < 4; ++it) {
        const int row = row0 + it * 16 + w * 4 + g;
        const bf16x8 v = *(const bf16x8*)&mk[(size_t)row * EE + l16 * 8];
        float p = 0.f;
        #pragma unroll
        for (int j = 0; j < 8; ++j) p += (float)v[j] * u[j];
        p += __shfl_xor(p, 1, 64);
        p += __shfl_xor(p, 2, 64);
        p += __shfl_xor(p, 4, 64);
        p += __shfl_xor(p, 8, 64);
        if (l16 == 0) out[row] = p * gp[row];
    }
}

// ---------------------------------------------------------------------------
// final softmax: block per b.
// ---------------------------------------------------------------------------
__global__ __launch_bounds__(256)
void softmax_final(const float* __restrict__ logits, float* __restrict__ soft)
{
    __shared__ float redm[4], reds[4];
    const int b = blockIdx.x, tid = threadIdx.x;
    const int lane = tid & 63, w = tid >> 6;
    const float* lb = logits + (size_t)b * MM;
    float v[8];
    float mx = -1e30f;
    #pragma unroll
    for (int i = 0; i < 8; ++i) { v[i] = lb[i * 256 + tid]; mx = fmaxf(mx, v[i]); }
    #pragma unroll
    for (int off = 32; off > 0; off >>= 1) mx = fmaxf(mx, __shfl_xor(mx, off, 64));
    if (lane == 0) redm[w] = mx;
    __syncthreads();
    mx = fmaxf(fmaxf(redm[0], redm[1]), fmaxf(redm[2], redm[3]));
    float sum = 0.f;
    #pragma unroll
    for (int i = 0; i < 8; ++i) { v[i] = __expf(v[i] - mx); sum += v[i]; }
    #pragma unroll
    for (int off = 32; off > 0; off >>= 1) sum += __shfl_xor(sum, off, 64);
    if (lane == 0) reds[w] = sum;
    __syncthreads();
    const float inv = 1.f / (reds[0] + reds[1] + reds[2] + reds[3]);
    #pragma unroll
    for (int i = 0; i < 8; ++i) soft[(size_t)b * MM + i * 256 + tid] = v[i] * inv;
}

// ---------------------------------------------------------------------------
extern "C" void kernel_launch(void* const* d_in, const int* in_sizes, int n_in,
                              void* d_out, int out_size, void* d_ws, size_t ws_size,
                              hipStream_t stream) {
    const int*   story    = (const int*)d_in[0];
    const int*   kb_len   = (const int*)d_in[1];
    const int*   conv_len = (const int*)d_in[2];
    // d_in[3] = hidden (dead w.r.t. outputs)
    const float* dh       = (const float*)d_in[4];
    const float* tf       = (const float*)d_in[5];
    const float* query    = (const float*)d_in[6];
    const float* gp       = (const float*)d_in[7];
    const float* C        = (const float*)d_in[8];
    const float* wA1      = (const float*)d_in[9];
    const float* bA1      = (const float*)d_in[10];
    const float* wA2      = (const float*)d_in[11];
    const float* bA2      = (const float*)d_in[12];
    // wC1/bC1/wC2/bC2, wf/bf: dead w.r.t. outputs

    char* ws = (char*)d_ws;
    const size_t M_ELEMS = (size_t)32768 * EE;
    size_t off = 0;
    __bf16* m   = (__bf16*)(ws + off); off += 2 * M_ELEMS * sizeof(__bf16);    // m1, m2
    __bf16* w1t = (__bf16*)(ws + off); off += 256 * 128 * sizeof(__bf16);
    __bf16* w2t = (__bf16*)(ws + off); off += 128 * 128 * sizeof(__bf16);
    float* lbuf = (float*)(ws + off);  off += (size_t)BB * MM * sizeof(float);
    float* uqA  = (float*)(ws + off);  off += (size_t)BB * EE * sizeof(float);
    float* uqB  = (float*)(ws + off);  off += (size_t)BB * EE * sizeof(float);

    float* out_soft   = (float*)d_out;
    float* out_logits = out_soft + (size_t)BB * MM;

    prep_small<<<N_PREP / 256, 256, 0, stream>>>(wA1, wA2, w1t, w2t, uqA, uqB);
    embed_mlp_mfma<<<3072, 256, 0, stream>>>(story, kb_len, conv_len, dh, tf, C,
                                             w1t, bA1, w2t, bA2, gp, query, m, lbuf);
    // hop1: uqA = m1^T(gp*soft0);  logits1 = gp*(m1 (query+uqA)) -> lbuf
    update_kernel<<<512, 256, 0, stream>>>(m, gp, lbuf, uqA);
    logits_kernel<<<512, 256, 0, stream>>>(m, gp, query, uqA, nullptr, lbuf);
    // hop2: uqB = m2^T(gp*soft1);  logits2 = gp*(m2 (query+uqA+uqB)) -> out
    update_kernel<<<512, 256, 0, stream>>>(m + M_ELEMS, gp, lbuf, uqB);
    logits_kernel<<<512, 256, 0, stream>>>(m + M_ELEMS, gp, query, uqA, uqB, out_logits);
    softmax_final<<<BB, 256, 0, stream>>>(out_logits, out_soft);
}